// Round 3
// baseline (122.277 us; speedup 1.0000x reference)
//
#include <hip/hip_runtime.h>
#include <hip/hip_bf16.h>

// Sizes
#define B_NODES 256
#define C_FEAT  64
#define Y_DIM   16
#define Z_PATH  23
#define E_ATTR  10
#define WXV     4096        // 16^3
#define K_REAL  368         // 16*23
#define K_PAD   384
#define M_DIM   16384       // 256*64
#define N_DIM   4096
#define ROWB    (K_PAD * 2) // 768 bytes per row (bf16)

typedef __attribute__((ext_vector_type(8))) short bf16x8;
typedef __attribute__((ext_vector_type(8))) unsigned short u16x8;
typedef __attribute__((ext_vector_type(4))) float f32x4;

__device__ inline unsigned short f2bf(float x) {
    union { float f; unsigned u; } v; v.f = x;
    unsigned r = v.u + 0x7fffu + ((v.u >> 16) & 1u);   // RNE
    return (unsigned short)(r >> 16);
}

__device__ inline void gload_lds16(const void* g, void* l) {
    __builtin_amdgcn_global_load_lds(
        (const __attribute__((address_space(1))) void*)g,
        (__attribute__((address_space(3))) void*)l,
        16, 0, 0);
}

// ---------------- fused prep: blocks [0,256) build A; blocks [256,1792) cast U
__global__ __launch_bounds__(256) void prep_combined(
    const float* __restrict__ U, const float* __restrict__ W,
    const float* __restrict__ z, const float* __restrict__ attr,
    unsigned short* __restrict__ A, unsigned short* __restrict__ Ub)
{
    int blk = blockIdx.x;
    int tid = threadIdx.x;
    if (blk < B_NODES) {
        int b = blk;
        __shared__ float t_lds[Z_PATH * C_FEAT];   // [k][c]
        __shared__ float z_lds[C_FEAT * Y_DIM];    // [c][i]
        __shared__ float a_lds[E_ATTR];
        if (tid < E_ATTR) a_lds[tid] = attr[b * E_ATTR + tid];
        ((float4*)z_lds)[tid] = ((const float4*)(z + (size_t)b * 1024))[tid];
        __syncthreads();
        for (int idx = tid; idx < Z_PATH * C_FEAT; idx += 256) {
            int k = idx >> 6;
            int c = idx & 63;
            float acc = 0.f;
            #pragma unroll
            for (int e = 0; e < E_ATTR; ++e)
                acc += a_lds[e] * W[(e * Z_PATH + k) * C_FEAT + c];
            t_lds[idx] = acc;
        }
        __syncthreads();
        unsigned short* Ab = A + (size_t)b * C_FEAT * K_PAD;
        for (int u = tid; u < C_FEAT * 48; u += 256) {
            int c = u / 48;
            int g = u - c * 48;
            int j0 = g * 8;
            u16x8 pack;
            #pragma unroll
            for (int jj = 0; jj < 8; ++jj) {
                int j = j0 + jj;
                float v = 0.f;
                if (j < K_REAL) {
                    int i = j / Z_PATH;
                    int k = j - i * Z_PATH;
                    v = z_lds[c * Y_DIM + i] * t_lds[k * C_FEAT + c];
                }
                pack[jj] = f2bf(v);
            }
            *(u16x8*)&Ab[c * K_PAD + j0] = pack;
        }
    } else {
        int f = (blk - B_NODES) * 256 + tid;       // [0, 4096*96)
        int row = f / 96;
        int q = f - row * 96;
        int j = q * 4;
        unsigned short o[4] = {0, 0, 0, 0};
        if (j < K_REAL) {
            float4 v = *(const float4*)(U + (size_t)row * K_REAL + j);
            o[0] = f2bf(v.x); o[1] = f2bf(v.y); o[2] = f2bf(v.z); o[3] = f2bf(v.w);
        }
        unsigned short* dst = Ub + (size_t)row * K_PAD + j;
        dst[0] = o[0]; dst[1] = o[1]; dst[2] = o[2]; dst[3] = o[3];
    }
}

// ---------------- GEMM 256x256 tile, BK=64, 8-phase-style schedule (T2+T3+T4+T5)
// C[16384][4096] = A[16384][384] x Bt[4096][384]^T (bf16 -> f32)
__global__ __launch_bounds__(512, 2) void gemm256(
    const unsigned short* __restrict__ A,
    const unsigned short* __restrict__ Bt,
    float* __restrict__ C)
{
    __shared__ __align__(16) unsigned short sA[2][256 * 64];
    __shared__ __align__(16) unsigned short sB[2][256 * 64];

    int bid = blockIdx.x;
    int wg = (bid & 7) * 128 + (bid >> 3);     // 1024 blocks, %8==0 -> bijective XCD swizzle
    int tm = wg >> 4;                          // 64 row-tiles
    int tn = wg & 15;                          // 16 col-tiles
    int tid = threadIdx.x;
    int lane = tid & 63;
    int w = tid >> 6;                          // 0..7
    int wm = w >> 2;                           // 0..1
    int wn = w & 3;                            // 0..3

    const char* gA = (const char*)A + (size_t)(tm * 256) * ROWB;
    const char* gB = (const char*)Bt + (size_t)(tn * 256) * ROWB;

    // staging constants: per half-tile (128 rows x 64 K), thread does 2 loads.
    // LDS dest linear; global source inverse-swizzled (slot ^= row&7).
    int chunk0 = w * 2;
    int srow = lane >> 3;                      // 0..7 (row within octet group)
    int gslot = (lane & 7) ^ srow;             // inverse-swizzled global 16B slot

    auto stage = [&](const char* gbase, unsigned short* lds, int t, int h) {
        #pragma unroll
        for (int L = 0; L < 2; ++L) {
            int chunk = chunk0 + L;            // 0..15
            gload_lds16(gbase + (size_t)(h * 128 + chunk * 8 + srow) * ROWB
                              + t * 128 + gslot * 16,
                        (char*)lds + h * 16384 + chunk * 1024);
        }
    };

    // fragment-read constants (swizzled): slot = (ks*4 + (lane>>4)) ^ (lane&7)
    int frow = lane & 15;
    int fsb = lane >> 4;                       // 0..3
    int fxor = lane & 7;

    auto rdA = [&](int b, int frag, int ks) -> bf16x8 {
        int row = wm * 128 + frag * 16 + frow;
        int slot = (ks * 4 + fsb) ^ fxor;
        return *(const bf16x8*)((const char*)&sA[b][0] + row * 128 + slot * 16);
    };
    auto rdB = [&](int b, int frag, int ks) -> bf16x8 {
        int row = wn * 64 + frag * 16 + frow;
        int slot = (ks * 4 + fsb) ^ fxor;
        return *(const bf16x8*)((const char*)&sB[b][0] + row * 128 + slot * 16);
    };

    f32x4 acc[8][4];
    #pragma unroll
    for (int p = 0; p < 8; ++p)
        #pragma unroll
        for (int q = 0; q < 4; ++q)
            acc[p][q] = (f32x4){0.f, 0.f, 0.f, 0.f};

    bf16x8 aq[4][2], bq[2][2][2];

    // prologue: T0{A0,A1,B0,B1}, T1{B0,B1}  (12 loads) -> wait all T0 (4 left)
    stage(gA, &sA[0][0], 0, 0); stage(gA, &sA[0][0], 0, 1);
    stage(gB, &sB[0][0], 0, 0); stage(gB, &sB[0][0], 0, 1);
    stage(gB, &sB[1][0], 1, 0); stage(gB, &sB[1][0], 1, 1);
    __builtin_amdgcn_sched_barrier(0);
    asm volatile("s_waitcnt vmcnt(4)" ::: "memory");
    __builtin_amdgcn_sched_barrier(0);
    __builtin_amdgcn_s_barrier();

    #pragma unroll
    for (int t = 0; t < 6; ++t) {
        const int b = t & 1;
        #pragma unroll
        for (int q = 0; q < 4; ++q) {
            const int mh = q >> 1;             // phases: (mh,nh) = 00,01,10,11
            const int nh = q & 1;
            // --- ds_reads for this phase (A reused across nh, B across mh)
            if (q == 0) {
                #pragma unroll
                for (int f = 0; f < 4; ++f)
                    #pragma unroll
                    for (int ks = 0; ks < 2; ++ks)
                        aq[f][ks] = rdA(b, f, ks);
                #pragma unroll
                for (int g = 0; g < 2; ++g)
                    #pragma unroll
                    for (int ks = 0; ks < 2; ++ks)
                        bq[0][g][ks] = rdB(b, g, ks);
            } else if (q == 1) {
                #pragma unroll
                for (int g = 0; g < 2; ++g)
                    #pragma unroll
                    for (int ks = 0; ks < 2; ++ks)
                        bq[1][g][ks] = rdB(b, 2 + g, ks);
            } else if (q == 2) {
                #pragma unroll
                for (int f = 0; f < 4; ++f)
                    #pragma unroll
                    for (int ks = 0; ks < 2; ++ks)
                        aq[f][ks] = rdA(b, 4 + f, ks);
            }
            // --- stage one half-tile (slots freed by barrier structure):
            // q0: A0(t+1) ; q1: A1(t+1) ; q2: B0(t+2) ; q3: B1(t+2)
            if (q == 0 && t + 1 < 6) stage(gA, &sA[(t + 1) & 1][0], t + 1, 0);
            if (q == 1 && t + 1 < 6) stage(gA, &sA[(t + 1) & 1][0], t + 1, 1);
            if (q == 2 && t + 2 < 6) stage(gB, &sB[b][0], t + 2, 0);
            if (q == 3 && t + 2 < 6) stage(gB, &sB[b][0], t + 2, 1);
            __builtin_amdgcn_sched_barrier(0);
            __builtin_amdgcn_s_barrier();
            asm volatile("s_waitcnt lgkmcnt(0)" ::: "memory");
            __builtin_amdgcn_sched_barrier(0);
            __builtin_amdgcn_s_setprio(1);
            #pragma unroll
            for (int f = 0; f < 4; ++f)
                #pragma unroll
                for (int g = 0; g < 2; ++g)
                    #pragma unroll
                    for (int ks = 0; ks < 2; ++ks)
                        acc[mh * 4 + f][nh * 2 + g] = __builtin_amdgcn_mfma_f32_16x16x32_bf16(
                            aq[f][ks], bq[nh][g][ks], acc[mh * 4 + f][nh * 2 + g], 0, 0, 0);
            __builtin_amdgcn_s_setprio(0);
            __builtin_amdgcn_sched_barrier(0);
            if (q == 3) {   // counted wait for NEXT tile's 4 halves (per-wave, then barrier)
                if (t < 4)       asm volatile("s_waitcnt vmcnt(4)" ::: "memory");
                else if (t == 4) asm volatile("s_waitcnt vmcnt(0)" ::: "memory");
                __builtin_amdgcn_sched_barrier(0);
            }
            if (!(t == 5 && q == 3)) __builtin_amdgcn_s_barrier();
        }
    }

    // epilogue: per-wave 128x64 output
    float* Cw = C + (size_t)(tm * 256 + wm * 128 + (lane >> 4) * 4) * N_DIM
                  + tn * 256 + wn * 64 + (lane & 15);
    #pragma unroll
    for (int fm = 0; fm < 8; ++fm)
        #pragma unroll
        for (int reg = 0; reg < 4; ++reg)
            #pragma unroll
            for (int fn = 0; fn < 4; ++fn)
                __builtin_nontemporal_store(acc[fm][fn][reg],
                    Cw + (size_t)(fm * 16 + reg) * N_DIM + fn * 16);
}

// ---------------- fallback (ws too small): direct f32, correct but slow
__global__ __launch_bounds__(256) void fallback_kernel(
    const float* __restrict__ U, const float* __restrict__ W,
    const float* __restrict__ z, const float* __restrict__ attr,
    float* __restrict__ out)
{
    int bc = blockIdx.x;
    int b = bc >> 6, c = bc & 63;
    int tid = threadIdx.x;
    __shared__ float zt[K_REAL];
    for (int idx = tid; idx < K_REAL; idx += 256) {
        int i = idx / Z_PATH;
        int k = idx - i * Z_PATH;
        float t = 0.f;
        #pragma unroll
        for (int e = 0; e < E_ATTR; ++e)
            t += attr[b * E_ATTR + e] * W[(e * Z_PATH + k) * C_FEAT + c];
        zt[idx] = z[((size_t)b * C_FEAT + c) * Y_DIM + i] * t;
    }
    __syncthreads();
    for (int n = tid; n < WXV; n += 256) {
        const float* Ur = U + (size_t)n * K_REAL;
        float s = 0.f;
        for (int j = 0; j < K_REAL; ++j) s += Ur[j] * zt[j];
        out[(size_t)bc * WXV + n] = s;
    }
}

extern "C" void kernel_launch(void* const* d_in, const int* in_sizes, int n_in,
                              void* d_out, int out_size, void* d_ws, size_t ws_size,
                              hipStream_t stream)
{
    const float* U    = (const float*)d_in[0];
    const float* W    = (const float*)d_in[1];
    const float* z    = (const float*)d_in[2];
    const float* attr = (const float*)d_in[3];
    float* out = (float*)d_out;

    size_t needA = (size_t)M_DIM * K_PAD * sizeof(unsigned short);
    size_t needU = (size_t)N_DIM * K_PAD * sizeof(unsigned short);
    if (ws_size >= needA + needU) {
        unsigned short* Abf = (unsigned short*)d_ws;
        unsigned short* Ubf = Abf + (size_t)M_DIM * K_PAD;
        prep_combined<<<B_NODES + (N_DIM * 96) / 256, 256, 0, stream>>>(U, W, z, attr, Abf, Ubf);
        gemm256<<<1024, 512, 0, stream>>>(Abf, Ubf, out);
    } else {
        fallback_kernel<<<M_DIM, 256, 0, stream>>>(U, W, z, attr, out);
    }
}

// Round 4
// 120.329 us; speedup vs baseline: 1.0162x; 1.0162x over previous
//
#include <hip/hip_runtime.h>
#include <hip/hip_bf16.h>

// Sizes
#define B_NODES 256
#define C_FEAT  64
#define Y_DIM   16
#define Z_PATH  23
#define E_ATTR  10
#define WXV     4096        // 16^3
#define K_REAL  368         // 16*23
#define K_PAD   384
#define M_DIM   16384       // 256*64
#define N_DIM   4096
#define ROWB    (K_PAD * 2) // 768 bytes per row (bf16)

typedef __attribute__((ext_vector_type(8))) short bf16x8;
typedef __attribute__((ext_vector_type(8))) unsigned short u16x8;
typedef __attribute__((ext_vector_type(4))) unsigned short u16x4;
typedef __attribute__((ext_vector_type(4))) float f32x4;

__device__ inline unsigned short f2bf(float x) {
    union { float f; unsigned u; } v; v.f = x;
    unsigned r = v.u + 0x7fffu + ((v.u >> 16) & 1u);   // RNE
    return (unsigned short)(r >> 16);
}

__device__ inline void gload_lds16(const void* g, void* l) {
    __builtin_amdgcn_global_load_lds(
        (const __attribute__((address_space(1))) void*)g,
        (__attribute__((address_space(3))) void*)l,
        16, 0, 0);
}

// ---------------- fused prep: blocks [0,256) build A; blocks [256,1792) cast U
__global__ __launch_bounds__(256) void prep_combined(
    const float* __restrict__ U, const float* __restrict__ W,
    const float* __restrict__ z, const float* __restrict__ attr,
    unsigned short* __restrict__ A, unsigned short* __restrict__ Ub)
{
    int blk = blockIdx.x;
    int tid = threadIdx.x;
    if (blk < B_NODES) {
        int b = blk;
        __shared__ float t_lds[Z_PATH * C_FEAT];   // [k][c]
        __shared__ float z_lds[C_FEAT * Y_DIM];    // [c][i]
        __shared__ float a_lds[E_ATTR];
        if (tid < E_ATTR) a_lds[tid] = attr[b * E_ATTR + tid];
        ((float4*)z_lds)[tid] = ((const float4*)(z + (size_t)b * 1024))[tid];
        __syncthreads();
        for (int idx = tid; idx < Z_PATH * C_FEAT; idx += 256) {
            int k = idx >> 6;
            int c = idx & 63;
            float acc = 0.f;
            #pragma unroll
            for (int e = 0; e < E_ATTR; ++e)
                acc += a_lds[e] * W[(e * Z_PATH + k) * C_FEAT + c];
            t_lds[idx] = acc;
        }
        __syncthreads();
        unsigned short* Ab = A + (size_t)b * C_FEAT * K_PAD;
        for (int u = tid; u < C_FEAT * 48; u += 256) {
            int c = u / 48;
            int g = u - c * 48;
            int j0 = g * 8;
            u16x8 pack;
            #pragma unroll
            for (int jj = 0; jj < 8; ++jj) {
                int j = j0 + jj;
                float v = 0.f;
                if (j < K_REAL) {
                    int i = j / Z_PATH;
                    int k = j - i * Z_PATH;
                    v = z_lds[c * Y_DIM + i] * t_lds[k * C_FEAT + c];
                }
                pack[jj] = f2bf(v);
            }
            *(u16x8*)&Ab[c * K_PAD + j0] = pack;
        }
    } else {
        int f = (blk - B_NODES) * 256 + tid;       // [0, 4096*96)
        int row = f / 96;
        int q = f - row * 96;
        int j = q * 4;
        u16x4 o = (u16x4){0, 0, 0, 0};
        if (j < K_REAL) {
            float4 v = *(const float4*)(U + (size_t)row * K_REAL + j);
            o[0] = f2bf(v.x); o[1] = f2bf(v.y); o[2] = f2bf(v.z); o[3] = f2bf(v.w);
        }
        *(u16x4*)&Ub[(size_t)row * K_PAD + j] = o;
    }
}

// ---------------- GEMM: C[16384][4096] = A[16384][384] x Bt[4096][384]^T (bf16 -> f32)
// 128x128 tile, BK=32, TRIPLE-buffered LDS (1 barrier/step), counted vmcnt,
// T2 LDS swizzle (slot ^= (row>>1)&3), hierarchical XCD/L2 swizzle.
__global__ __launch_bounds__(256) void gemm_kernel(
    const unsigned short* __restrict__ A,
    const unsigned short* __restrict__ Bt,
    float* __restrict__ C)
{
    __shared__ __align__(16) unsigned short sA[3][128 * 32];
    __shared__ __align__(16) unsigned short sB[3][128 * 32];

    // hierarchical swizzle: XCD x owns tm in [16x, 16x+16); within XCD,
    // 4 chunks of 8 tn, tm-inner -> L2 window ~= 12 A-panels + 8 B-panels ~2MB
    int bid = blockIdx.x;
    int x = bid & 7;                 // XCD
    int r = bid >> 3;                // 0..511
    int chunk = r >> 7;              // 0..3 (tn group)
    int i = r & 127;
    int tm = x * 16 + (i >> 3);      // 0..127
    int tn = chunk * 8 + (i & 7);    // 0..31

    int tid = threadIdx.x;
    int lane = tid & 63;
    int w = tid >> 6;
    int wm = w >> 1, wn = w & 1;

    f32x4 acc[4][4];
    #pragma unroll
    for (int p = 0; p < 4; ++p)
        #pragma unroll
        for (int q = 0; q < 4; ++q)
            acc[p][q] = (f32x4){0.f, 0.f, 0.f, 0.f};

    const char* gA = (const char*)A + (size_t)(tm * 128) * ROWB;
    const char* gB = (const char*)Bt + (size_t)(tn * 128) * ROWB;
    int ch0 = w * 2;
    int lrow = lane >> 2;                            // row within 16-row chunk
    // T2: LDS[row][slot] holds G[row][slot ^ ((row>>1)&3)]; gload dest is linear
    // (base + lane*16), so pre-swizzle the SOURCE column:
    int lk16 = ((lane & 3) ^ ((lane >> 3) & 3)) * 16;

    auto stage = [&](int t, int buf) {
        #pragma unroll
        for (int s = 0; s < 2; ++s) {
            int ch = ch0 + s;
            int rr = ch * 16 + lrow;
            gload_lds16(gA + (size_t)rr * ROWB + t * 64 + lk16,
                        (char*)&sA[buf][0] + ch * 1024);
            gload_lds16(gB + (size_t)rr * ROWB + t * 64 + lk16,
                        (char*)&sB[buf][0] + ch * 1024);
        }
    };

    int fr_row = lane & 15;
    // swizzled fragment read slot: (lane>>4) ^ ((fr_row>>1)&3), 16B units
    int fslot = ((lane >> 4) ^ ((fr_row >> 1) & 3)) * 16;

    // prologue: prefetch tiles 0 and 1
    stage(0, 0);
    stage(1, 1);
    __builtin_amdgcn_sched_barrier(0);
    asm volatile("s_waitcnt vmcnt(4)" ::: "memory");   // tile 0 landed
    __builtin_amdgcn_sched_barrier(0);
    __builtin_amdgcn_s_barrier();

    #pragma unroll
    for (int t = 0; t < 12; ++t) {
        const int cur = t % 3;
        if (t < 10) stage(t + 2, (t + 2) % 3);         // overwrites buf freed at t-1
        bf16x8 af[4], bfr[4];
        #pragma unroll
        for (int fm = 0; fm < 4; ++fm)
            af[fm] = *(const bf16x8*)((const char*)&sA[cur][0]
                     + (wm * 64 + fm * 16 + fr_row) * 64 + fslot);
        #pragma unroll
        for (int fn = 0; fn < 4; ++fn)
            bfr[fn] = *(const bf16x8*)((const char*)&sB[cur][0]
                     + (wn * 64 + fn * 16 + fr_row) * 64 + fslot);
        #pragma unroll
        for (int fm = 0; fm < 4; ++fm)
            #pragma unroll
            for (int fn = 0; fn < 4; ++fn)
                acc[fm][fn] = __builtin_amdgcn_mfma_f32_16x16x32_bf16(
                    af[fm], bfr[fn], acc[fm][fn], 0, 0, 0);
        __builtin_amdgcn_sched_barrier(0);
        if (t < 10)       { asm volatile("s_waitcnt vmcnt(4)" ::: "memory"); }
        else if (t == 10) { asm volatile("s_waitcnt vmcnt(0)" ::: "memory"); }
        __builtin_amdgcn_sched_barrier(0);
        if (t < 11) __builtin_amdgcn_s_barrier();
    }

    int r0 = tm * 128 + wm * 64 + (lane >> 4) * 4;
    int c0 = tn * 128 + wn * 64 + (lane & 15);
    #pragma unroll
    for (int fm = 0; fm < 4; ++fm)
        #pragma unroll
        for (int fn = 0; fn < 4; ++fn)
            #pragma unroll
            for (int reg = 0; reg < 4; ++reg)
                __builtin_nontemporal_store(acc[fm][fn][reg],
                    &C[(size_t)(r0 + fm * 16 + reg) * N_DIM + (c0 + fn * 16)]);
}

// ---------------- fallback (ws too small): direct f32, correct but slow
__global__ __launch_bounds__(256) void fallback_kernel(
    const float* __restrict__ U, const float* __restrict__ W,
    const float* __restrict__ z, const float* __restrict__ attr,
    float* __restrict__ out)
{
    int bc = blockIdx.x;
    int b = bc >> 6, c = bc & 63;
    int tid = threadIdx.x;
    __shared__ float zt[K_REAL];
    for (int idx = tid; idx < K_REAL; idx += 256) {
        int i = idx / Z_PATH;
        int k = idx - i * Z_PATH;
        float t = 0.f;
        #pragma unroll
        for (int e = 0; e < E_ATTR; ++e)
            t += attr[b * E_ATTR + e] * W[(e * Z_PATH + k) * C_FEAT + c];
        zt[idx] = z[((size_t)b * C_FEAT + c) * Y_DIM + i] * t;
    }
    __syncthreads();
    for (int n = tid; n < WXV; n += 256) {
        const float* Ur = U + (size_t)n * K_REAL;
        float s = 0.f;
        for (int j = 0; j < K_REAL; ++j) s += Ur[j] * zt[j];
        out[(size_t)bc * WXV + n] = s;
    }
}

extern "C" void kernel_launch(void* const* d_in, const int* in_sizes, int n_in,
                              void* d_out, int out_size, void* d_ws, size_t ws_size,
                              hipStream_t stream)
{
    const float* U    = (const float*)d_in[0];
    const float* W    = (const float*)d_in[1];
    const float* z    = (const float*)d_in[2];
    const float* attr = (const float*)d_in[3];
    float* out = (float*)d_out;

    size_t needA = (size_t)M_DIM * K_PAD * sizeof(unsigned short);
    size_t needU = (size_t)N_DIM * K_PAD * sizeof(unsigned short);
    if (ws_size >= needA + needU) {
        unsigned short* Abf = (unsigned short*)d_ws;
        unsigned short* Ubf = Abf + (size_t)M_DIM * K_PAD;
        prep_combined<<<B_NODES + (N_DIM * 96) / 256, 256, 0, stream>>>(U, W, z, attr, Abf, Ubf);
        gemm_kernel<<<4096, 256, 0, stream>>>(Abf, Ubf, out);
    } else {
        fallback_kernel<<<M_DIM, 256, 0, stream>>>(U, W, z, attr, out);
    }
}

// Round 5
// 105.846 us; speedup vs baseline: 1.1552x; 1.1368x over previous
//
#include <hip/hip_runtime.h>
#include <hip/hip_bf16.h>

// Sizes
#define B_NODES 256
#define C_FEAT  64
#define Y_DIM   16
#define Z_PATH  23
#define E_ATTR  10
#define WXV     4096        // 16^3
#define K_REAL  368         // 16*23
#define K_PAD   384
#define M_DIM   16384       // 256*64
#define N_DIM   4096
#define ROWB    (K_PAD * 2) // 768 bytes per row (bf16)

typedef __attribute__((ext_vector_type(8))) short bf16x8;
typedef __attribute__((ext_vector_type(8))) unsigned short u16x8;
typedef __attribute__((ext_vector_type(4))) unsigned short u16x4;
typedef __attribute__((ext_vector_type(4))) float f32x4;

__device__ inline unsigned short f2bf(float x) {
    union { float f; unsigned u; } v; v.f = x;
    unsigned r = v.u + 0x7fffu + ((v.u >> 16) & 1u);   // RNE
    return (unsigned short)(r >> 16);
}

__device__ inline void gload_lds16(const void* g, void* l) {
    __builtin_amdgcn_global_load_lds(
        (const __attribute__((address_space(1))) void*)g,
        (__attribute__((address_space(3))) void*)l,
        16, 0, 0);
}

// ---------------- fused prep: blocks [0,256) build A; blocks [256,1792) cast U
__global__ __launch_bounds__(256) void prep_combined(
    const float* __restrict__ U, const float* __restrict__ W,
    const float* __restrict__ z, const float* __restrict__ attr,
    unsigned short* __restrict__ A, unsigned short* __restrict__ Ub)
{
    int blk = blockIdx.x;
    int tid = threadIdx.x;
    if (blk < B_NODES) {
        int b = blk;
        __shared__ float t_lds[Z_PATH * C_FEAT];   // [k][c]
        __shared__ float z_lds[C_FEAT * Y_DIM];    // [c][i]
        __shared__ float a_lds[E_ATTR];
        if (tid < E_ATTR) a_lds[tid] = attr[b * E_ATTR + tid];
        ((float4*)z_lds)[tid] = ((const float4*)(z + (size_t)b * 1024))[tid];
        __syncthreads();
        for (int idx = tid; idx < Z_PATH * C_FEAT; idx += 256) {
            int k = idx >> 6;
            int c = idx & 63;
            float acc = 0.f;
            #pragma unroll
            for (int e = 0; e < E_ATTR; ++e)
                acc += a_lds[e] * W[(e * Z_PATH + k) * C_FEAT + c];
            t_lds[idx] = acc;
        }
        __syncthreads();
        unsigned short* Ab = A + (size_t)b * C_FEAT * K_PAD;
        for (int u = tid; u < C_FEAT * 48; u += 256) {
            int c = u / 48;
            int g = u - c * 48;
            int j0 = g * 8;
            u16x8 pack;
            #pragma unroll
            for (int jj = 0; jj < 8; ++jj) {
                int j = j0 + jj;
                float v = 0.f;
                if (j < K_REAL) {
                    int i = j / Z_PATH;
                    int k = j - i * Z_PATH;
                    v = z_lds[c * Y_DIM + i] * t_lds[k * C_FEAT + c];
                }
                pack[jj] = f2bf(v);
            }
            *(u16x8*)&Ab[c * K_PAD + j0] = pack;
        }
    } else {
        int f = (blk - B_NODES) * 256 + tid;       // [0, 4096*96)
        int row = f / 96;
        int q = f - row * 96;
        int j = q * 4;
        u16x4 o = (u16x4){0, 0, 0, 0};
        if (j < K_REAL) {
            float4 v = *(const float4*)(U + (size_t)row * K_REAL + j);
            o[0] = f2bf(v.x); o[1] = f2bf(v.y); o[2] = f2bf(v.z); o[3] = f2bf(v.w);
        }
        *(u16x4*)&Ub[(size_t)row * K_PAD + j] = o;
    }
}

// ---------------- GEMM: C[16384][4096] = A[16384][384] x Bt[4096][384]^T (bf16 -> f32)
// EXACT round-2 structure (128x128, BK=32, dbuf, 2 barriers/step, counted vmcnt,
// flat %8 XCD swizzle, NT stores) + ONLY change: T2 LDS swizzle slot^=(row>>1)&3
__global__ __launch_bounds__(256) void gemm_kernel(
    const unsigned short* __restrict__ A,
    const unsigned short* __restrict__ Bt,
    float* __restrict__ C)
{
    __shared__ __align__(16) unsigned short sA[2][128 * 32];
    __shared__ __align__(16) unsigned short sB[2][128 * 32];

    int bid = blockIdx.x;
    int wg = (bid & 7) * 512 + (bid >> 3);     // XCD swizzle (4096 % 8 == 0, bijective)
    int tm = wg >> 5;                          // 128 row-tiles
    int tn = wg & 31;                          // 32 col-tiles
    int tid = threadIdx.x;
    int lane = tid & 63;
    int w = tid >> 6;
    int wm = w >> 1, wn = w & 1;

    f32x4 acc[4][4];
    #pragma unroll
    for (int p = 0; p < 4; ++p)
        #pragma unroll
        for (int q = 0; q < 4; ++q)
            acc[p][q] = (f32x4){0.f, 0.f, 0.f, 0.f};

    const char* gA = (const char*)A + (size_t)(tm * 128) * ROWB;
    const char* gB = (const char*)Bt + (size_t)(tn * 128) * ROWB;
    int ch0 = w * 2;
    int lrow = lane >> 2;            // 0..15 rows within chunk
    // T2 swizzle: LDS[row][slot] = G[row][slot ^ ((row>>1)&3)]; gload dest is
    // linear (base + lane*16, row=lane>>2, slot=lane&3) -> pre-swizzle SOURCE col:
    int lk16 = ((lane & 3) ^ ((lane >> 3) & 3)) * 16;

    auto stage = [&](int t, int buf) {
        #pragma unroll
        for (int s = 0; s < 2; ++s) {
            int ch = ch0 + s;
            int r = ch * 16 + lrow;
            gload_lds16(gA + (size_t)r * ROWB + t * 64 + lk16,
                        (char*)&sA[buf][0] + ch * 1024);
            gload_lds16(gB + (size_t)r * ROWB + t * 64 + lk16,
                        (char*)&sB[buf][0] + ch * 1024);
        }
    };

    int fr_row = lane & 15;
    // swizzled fragment read: want G[row][lane>>4] -> LDS slot (lane>>4)^((row>>1)&3)
    int fslot = ((lane >> 4) ^ ((fr_row >> 1) & 3)) * 16;

    // prologue: prefetch tiles 0 and 1
    stage(0, 0);
    stage(1, 1);
    __builtin_amdgcn_sched_barrier(0);
    asm volatile("s_waitcnt vmcnt(4)" ::: "memory");   // tile 0 landed
    __builtin_amdgcn_sched_barrier(0);
    __builtin_amdgcn_s_barrier();

    #pragma unroll
    for (int t = 0; t < 12; ++t) {
        const int cur = t & 1;
        bf16x8 af[4], bfr[4];
        #pragma unroll
        for (int fm = 0; fm < 4; ++fm)
            af[fm] = *(const bf16x8*)((const char*)&sA[cur][0]
                     + (wm * 64 + fm * 16 + fr_row) * 64 + fslot);
        #pragma unroll
        for (int fn = 0; fn < 4; ++fn)
            bfr[fn] = *(const bf16x8*)((const char*)&sB[cur][0]
                     + (wn * 64 + fn * 16 + fr_row) * 64 + fslot);
        #pragma unroll
        for (int fm = 0; fm < 4; ++fm)
            #pragma unroll
            for (int fn = 0; fn < 4; ++fn)
                acc[fm][fn] = __builtin_amdgcn_mfma_f32_16x16x32_bf16(
                    af[fm], bfr[fn], acc[fm][fn], 0, 0, 0);
        if (t < 11) {
            __builtin_amdgcn_sched_barrier(0);
            __builtin_amdgcn_s_barrier();              // A: all waves done reading buf[cur]
            if (t < 10) stage(t + 2, cur);             // async overwrite of buf[cur]
            __builtin_amdgcn_sched_barrier(0);         // pin stage-issue BEFORE counted wait
            if (t < 10) { asm volatile("s_waitcnt vmcnt(4)" ::: "memory"); }
            else        { asm volatile("s_waitcnt vmcnt(0)" ::: "memory"); }
            __builtin_amdgcn_sched_barrier(0);
            __builtin_amdgcn_s_barrier();              // B: buf[t+1] ready for all
            __builtin_amdgcn_sched_barrier(0);         // keep next iter's ds_reads below
        }
    }

    int r0 = tm * 128 + wm * 64 + (lane >> 4) * 4;
    int c0 = tn * 128 + wn * 64 + (lane & 15);
    #pragma unroll
    for (int fm = 0; fm < 4; ++fm)
        #pragma unroll
        for (int fn = 0; fn < 4; ++fn)
            #pragma unroll
            for (int reg = 0; reg < 4; ++reg)
                __builtin_nontemporal_store(acc[fm][fn][reg],
                    &C[(size_t)(r0 + fm * 16 + reg) * N_DIM + (c0 + fn * 16)]);
}

// ---------------- fallback (ws too small): direct f32, correct but slow
__global__ __launch_bounds__(256) void fallback_kernel(
    const float* __restrict__ U, const float* __restrict__ W,
    const float* __restrict__ z, const float* __restrict__ attr,
    float* __restrict__ out)
{
    int bc = blockIdx.x;
    int b = bc >> 6, c = bc & 63;
    int tid = threadIdx.x;
    __shared__ float zt[K_REAL];
    for (int idx = tid; idx < K_REAL; idx += 256) {
        int i = idx / Z_PATH;
        int k = idx - i * Z_PATH;
        float t = 0.f;
        #pragma unroll
        for (int e = 0; e < E_ATTR; ++e)
            t += attr[b * E_ATTR + e] * W[(e * Z_PATH + k) * C_FEAT + c];
        zt[idx] = z[((size_t)b * C_FEAT + c) * Y_DIM + i] * t;
    }
    __syncthreads();
    for (int n = tid; n < WXV; n += 256) {
        const float* Ur = U + (size_t)n * K_REAL;
        float s = 0.f;
        for (int j = 0; j < K_REAL; ++j) s += Ur[j] * zt[j];
        out[(size_t)bc * WXV + n] = s;
    }
}

extern "C" void kernel_launch(void* const* d_in, const int* in_sizes, int n_in,
                              void* d_out, int out_size, void* d_ws, size_t ws_size,
                              hipStream_t stream)
{
    const float* U    = (const float*)d_in[0];
    const float* W    = (const float*)d_in[1];
    const float* z    = (const float*)d_in[2];
    const float* attr = (const float*)d_in[3];
    float* out = (float*)d_out;

    size_t needA = (size_t)M_DIM * K_PAD * sizeof(unsigned short);
    size_t needU = (size_t)N_DIM * K_PAD * sizeof(unsigned short);
    if (ws_size >= needA + needU) {
        unsigned short* Abf = (unsigned short*)d_ws;
        unsigned short* Ubf = Abf + (size_t)M_DIM * K_PAD;
        prep_combined<<<B_NODES + (N_DIM * 96) / 256, 256, 0, stream>>>(U, W, z, attr, Abf, Ubf);
        gemm_kernel<<<4096, 256, 0, stream>>>(Abf, Ubf, out);
    } else {
        fallback_kernel<<<M_DIM, 256, 0, stream>>>(U, W, z, attr, out);
    }
}